// Round 3
// baseline (642.820 us; speedup 1.0000x reference)
//
#include <hip/hip_runtime.h>
#include <math.h>

// B=16, H=64, W=64, C=256; M=65536 pixels. Input/output dtype (fp32 vs bf16)
// detected AT RUNTIME on device (g_flag: 0=bf16, 1=fp32) by scanning h for
// bf16-inf/NaN bit patterns (impossible in real bf16 Gaussian data, ~32
// expected hits in fp32 low halves). All intermediates in __device__ globals
// (d_ws unused). Compute: bf16 MFMA, fp32 accumulation.

typedef unsigned short u16;
typedef __bf16 bf16x8 __attribute__((ext_vector_type(8)));
typedef float floatx4 __attribute__((ext_vector_type(4)));

__device__ int g_flag;  // 0 = bf16 inputs, 1 = fp32 inputs
__device__ __align__(16) u16 g_h[16777216];     // canonical bf16 h  [65536,256]
__device__ __align__(16) u16 g_perc[50331648];  // perceived/qkv     [65536,768]
__device__ __align__(16) u16 g_hid[33554432];   // hid               [65536,512]
__device__ __align__(16) u16 g_hnew[16777216];  // h_new             [65536,256]
__device__ __align__(16) u16 g_wperc[6912];
__device__ __align__(16) u16 g_bperc[768];
__device__ __align__(16) u16 g_wup1[393216];
__device__ __align__(16) u16 g_bup1[512];
__device__ __align__(16) u16 g_wup2[131072];
__device__ __align__(16) u16 g_bup2[256];
__device__ __align__(16) u16 g_wqkv[196608];
__device__ __align__(16) u16 g_bqkv[768];

__device__ __forceinline__ float b2f(u16 x) {
  unsigned int u = ((unsigned int)x) << 16;
  float f;
  __builtin_memcpy(&f, &u, 4);
  return f;
}
__device__ __forceinline__ u16 f2b(float f) {
  unsigned int u;
  __builtin_memcpy(&u, &f, 4);
  u += 0x7FFFu + ((u >> 16) & 1u);  // round-to-nearest-even
  return (u16)(u >> 16);
}

// --------------------------------------------------------------------------
// dtype probe: even u16 indices of fp32 data are uniform-random (mantissa low
// bits) -> hit (v&0x7F80)==0x7F80 w.p. 1/256. Real bf16 N(0,1) data: never.
// --------------------------------------------------------------------------
__global__ __launch_bounds__(256) void probe_kernel(const u16* __restrict__ h) {
  __shared__ int hit;
  if (threadIdx.x == 0) hit = 0;
  __syncthreads();
  int local = 0;
  for (int i = threadIdx.x; i < 8192; i += 256) {
    u16 v = h[2 * i];
    if ((v & 0x7F80) == 0x7F80) local = 1;
  }
  if (local) atomicOr(&hit, 1);
  __syncthreads();
  if (threadIdx.x == 0) g_flag = hit;
}

// --------------------------------------------------------------------------
// canonicalize input tensor -> bf16 device global (selector picks dst).
// --------------------------------------------------------------------------
__device__ __forceinline__ u16* dst_of(int which) {
  switch (which) {
    case 0: return g_h;
    case 1: return g_wperc;
    case 2: return g_bperc;
    case 3: return g_wup1;
    case 4: return g_bup1;
    case 5: return g_wup2;
    case 6: return g_bup2;
    case 7: return g_wqkv;
    default: return g_bqkv;
  }
}
__global__ __launch_bounds__(256) void conv_kernel(const void* __restrict__ in,
                                                   int n, int which) {
  u16* out = dst_of(which);
  const int fp32 = g_flag;
  for (int i = blockIdx.x * 256 + threadIdx.x; i < n; i += gridDim.x * 256) {
    out[i] = fp32 ? f2b(((const float*)in)[i]) : ((const u16*)in)[i];
  }
}

// --------------------------------------------------------------------------
// grouped 3x3 perception conv (groups=C, 3 outs/group). Block=(b,y) row,
// thread=input channel c. g_h -> g_perc [pix][768].
// --------------------------------------------------------------------------
__global__ __launch_bounds__(256) void perc_kernel() {
  const int by = blockIdx.x;  // b*64 + y
  const int b = by >> 6, y = by & 63;
  const int c = threadIdx.x;
  float w[3][9], bias[3];
#pragma unroll
  for (int t = 0; t < 3; ++t) {
    bias[t] = b2f(g_bperc[3 * c + t]);
#pragma unroll
    for (int j = 0; j < 9; ++j) w[t][j] = b2f(g_wperc[(3 * c + t) * 9 + j]);
  }
  for (int x = 0; x < 64; ++x) {
    float hv[9];
#pragma unroll
    for (int j = 0; j < 9; ++j) {
      int dy = j / 3 - 1, dx = j % 3 - 1;
      int yy = y + dy, xx = x + dx;
      bool ok = ((unsigned)yy < 64u) && ((unsigned)xx < 64u);
      hv[j] = ok ? b2f(g_h[(((size_t)(b * 64 + yy) * 64 + xx) << 8) + c]) : 0.0f;
    }
    const size_t pix = (size_t)(b * 64 + y) * 64 + x;
#pragma unroll
    for (int t = 0; t < 3; ++t) {
      float a = bias[t];
#pragma unroll
      for (int j = 0; j < 9; ++j) a += hv[j] * w[t][j];
      g_perc[pix * 768 + 3 * c + t] = f2b(a);
    }
  }
}

// --------------------------------------------------------------------------
// MFMA bf16 GEMM: C[M,N] = epi(A[M,K] * W[N,K]^T + bias[N])
// BM=BN=128, BK=32, 4 waves 2x2, each 64x64 via 4x4 mfma_f32_16x16x32_bf16.
// MODE 0: perceived@wup1 +GELU -> hid.  MODE 1: hid@wup2 +h -> hnew.
// MODE 2: hnew@wqkv -> qkv (g_perc reuse).
// --------------------------------------------------------------------------
template <int MODE>
__global__ __launch_bounds__(256) void gemm_bt(int M, int N, int K) {
  const u16 *A, *Bw, *bias, *resid;
  u16* C;
  if (MODE == 0) { A = g_perc; Bw = g_wup1; bias = g_bup1; resid = nullptr; C = g_hid; }
  if (MODE == 1) { A = g_hid;  Bw = g_wup2; bias = g_bup2; resid = g_h;     C = g_hnew; }
  if (MODE == 2) { A = g_hnew; Bw = g_wqkv; bias = g_bqkv; resid = nullptr; C = g_perc; }

  __shared__ __align__(16) u16 Al[128 * 40];
  __shared__ __align__(16) u16 Bl[128 * 40];
  const int tid = threadIdx.x;
  const int wave = tid >> 6, lane = tid & 63;
  const int ln = lane & 15, quad = lane >> 4;
  const int m0 = blockIdx.y * 128, n0 = blockIdx.x * 128;
  const int wm = (wave >> 1) * 64, wn = (wave & 1) * 64;
  floatx4 acc[4][4] = {};

  for (int k0 = 0; k0 < K; k0 += 32) {
#pragma unroll
    for (int part = 0; part < 2; ++part) {
      int u = tid + part * 256;  // 512 uint4 per tile
      int row = u >> 2, cc = (u & 3) * 8;
      *(uint4*)(&Al[row * 40 + cc]) =
          *(const uint4*)(&A[(size_t)(m0 + row) * K + k0 + cc]);
      *(uint4*)(&Bl[row * 40 + cc]) =
          *(const uint4*)(&Bw[(size_t)(n0 + row) * K + k0 + cc]);
    }
    __syncthreads();
    bf16x8 af[4], bfr[4];
#pragma unroll
    for (int i = 0; i < 4; ++i)
      af[i] = *(const bf16x8*)(&Al[(wm + i * 16 + ln) * 40 + quad * 8]);
#pragma unroll
    for (int j = 0; j < 4; ++j)
      bfr[j] = *(const bf16x8*)(&Bl[(wn + j * 16 + ln) * 40 + quad * 8]);
#pragma unroll
    for (int i = 0; i < 4; ++i)
#pragma unroll
      for (int j = 0; j < 4; ++j)
        acc[i][j] = __builtin_amdgcn_mfma_f32_16x16x32_bf16(af[i], bfr[j],
                                                            acc[i][j], 0, 0, 0);
    __syncthreads();
  }

#pragma unroll
  for (int i = 0; i < 4; ++i) {
#pragma unroll
    for (int rr = 0; rr < 4; ++rr) {
      const int m = m0 + wm + i * 16 + quad * 4 + rr;
#pragma unroll
      for (int j = 0; j < 4; ++j) {
        const int n = n0 + wn + j * 16 + ln;
        float v = acc[i][j][rr] + b2f(bias[n]);
        if (MODE == 0) v = 0.5f * v * (1.0f + erff(v * 0.70710678118654752f));
        if (MODE == 1) v += b2f(resid[(size_t)m * N + n]);
        C[(size_t)m * N + n] = f2b(v);
      }
    }
  }
}

// --------------------------------------------------------------------------
// 3x3 windowed local attention (zero-padded borders). One wave per pixel,
// lane = 4 channels. OOB neighbor => score 0 in softmax, zero value.
// out = hnew + attn, dtype per g_flag.
// --------------------------------------------------------------------------
__global__ __launch_bounds__(256) void attn_kernel(void* __restrict__ outv) {
  const int wave = threadIdx.x >> 6, lane = threadIdx.x & 63;
  const int pix = blockIdx.x * 4 + wave;
  const int y = (pix >> 6) & 63, x = pix & 63;
  const int c0 = lane * 4;
  const u16* qp = g_perc + (size_t)pix * 768 + c0;
  const float q0 = b2f(qp[0]), q1 = b2f(qp[1]), q2 = b2f(qp[2]), q3 = b2f(qp[3]);
  float s[9];
  int nidx[9];
#pragma unroll
  for (int j = 0; j < 9; ++j) {
    const int dy = j / 3 - 1, dx = j % 3 - 1;
    const int yy = y + dy, xx = x + dx;
    const bool ok = ((unsigned)yy < 64u) && ((unsigned)xx < 64u);
    const int np = pix + dy * 64 + dx;  // same image when ok
    nidx[j] = ok ? np : -1;
    float p = 0.0f;
    if (ok) {
      const u16* kp = g_perc + (size_t)np * 768 + 256 + c0;
      p = q0 * b2f(kp[0]) + q1 * b2f(kp[1]) + q2 * b2f(kp[2]) + q3 * b2f(kp[3]);
    }
#pragma unroll
    for (int off = 32; off >= 1; off >>= 1) p += __shfl_xor(p, off, 64);
    s[j] = p * 0.0625f;  // 1/sqrt(256)
  }
  float mx = s[0];
#pragma unroll
  for (int j = 1; j < 9; ++j) mx = fmaxf(mx, s[j]);
  float e[9], den = 0.0f;
#pragma unroll
  for (int j = 0; j < 9; ++j) {
    e[j] = expf(s[j] - mx);
    den += e[j];
  }
  const float inv = 1.0f / den;
  const u16* hp = g_hnew + (size_t)pix * 256 + c0;
  float a0 = b2f(hp[0]), a1 = b2f(hp[1]), a2 = b2f(hp[2]), a3 = b2f(hp[3]);
#pragma unroll
  for (int j = 0; j < 9; ++j) {
    if (nidx[j] >= 0) {
      const float wgt = e[j] * inv;
      const u16* vp = g_perc + (size_t)nidx[j] * 768 + 512 + c0;
      a0 += wgt * b2f(vp[0]);
      a1 += wgt * b2f(vp[1]);
      a2 += wgt * b2f(vp[2]);
      a3 += wgt * b2f(vp[3]);
    }
  }
  const size_t o = (size_t)pix * 256 + c0;
  if (g_flag) {
    float* op = (float*)outv + o;
    op[0] = a0; op[1] = a1; op[2] = a2; op[3] = a3;
  } else {
    u16* op = (u16*)outv + o;
    op[0] = f2b(a0); op[1] = f2b(a1); op[2] = f2b(a2); op[3] = f2b(a3);
  }
}

// --------------------------------------------------------------------------
extern "C" void kernel_launch(void* const* d_in, const int* in_sizes, int n_in,
                              void* d_out, int out_size, void* d_ws,
                              size_t ws_size, hipStream_t stream) {
  (void)d_ws; (void)ws_size;
  // 0) detect input dtype on device
  probe_kernel<<<1, 256, 0, stream>>>((const u16*)d_in[0]);
  // 1) canonicalize all 9 inputs to bf16 device globals
  static const int sizes[9] = {16777216, 6912, 768, 393216, 512,
                               131072,   256,  196608, 768};
  for (int i = 0; i < 9; ++i) {
    int n = sizes[i];
    int grid = (n + 2047) / 2048;
    if (grid > 8192) grid = 8192;
    conv_kernel<<<grid, 256, 0, stream>>>(d_in[i], n, i);
  }
  // 2) perception (depthwise 3x3, 3 taps/channel)
  perc_kernel<<<1024, 256, 0, stream>>>();
  // 3) hid = GELU(perceived @ w_up1^T + b_up1)   [65536 x 512, K=768]
  gemm_bt<0><<<dim3(4, 512), 256, 0, stream>>>(65536, 512, 768);
  // 4) h_new = h + hid @ w_up2^T + b_up2         [65536 x 256, K=512]
  gemm_bt<1><<<dim3(2, 512), 256, 0, stream>>>(65536, 256, 512);
  // 5) qkv = h_new @ w_qkv^T + b_qkv             [65536 x 768, K=256]
  gemm_bt<2><<<dim3(6, 512), 256, 0, stream>>>(65536, 768, 256);
  // 6) out = h_new + local_attn(qkv)
  attn_kernel<<<16384, 256, 0, stream>>>(d_out);
}

// Round 4
// 576.042 us; speedup vs baseline: 1.1159x; 1.1159x over previous
//
#include <hip/hip_runtime.h>
#include <math.h>

// B=16, H=64, W=64, C=256; M=65536 pixels. Input dtype (fp32 confirmed by
// round-3 probe, but detection kept for robustness) canonicalized to bf16
// device globals. Compute: bf16 MFMA (16x16x32), fp32 accumulation.
// R4 changes: global_load_lds(16B) staging + unpadded LDS (stride 32),
// XCD-aware block swizzle (same-A blocks share an XCD's L2), uint2 attn
// loads, fused converters (8 launches/iter total).

typedef unsigned short u16;
typedef __bf16 bf16x8 __attribute__((ext_vector_type(8)));
typedef float floatx4 __attribute__((ext_vector_type(4)));

__device__ int g_flag;  // 0 = bf16 inputs, 1 = fp32 inputs
__device__ __align__(16) u16 g_h[16777216];     // canonical bf16 h  [65536,256]
__device__ __align__(16) u16 g_perc[50331648];  // perceived/qkv     [65536,768]
__device__ __align__(16) u16 g_hid[33554432];   // hid               [65536,512]
__device__ __align__(16) u16 g_hnew[16777216];  // h_new             [65536,256]
__device__ __align__(16) u16 g_wperc[6912];
__device__ __align__(16) u16 g_bperc[768];
__device__ __align__(16) u16 g_wup1[393216];
__device__ __align__(16) u16 g_bup1[512];
__device__ __align__(16) u16 g_wup2[131072];
__device__ __align__(16) u16 g_bup2[256];
__device__ __align__(16) u16 g_wqkv[196608];
__device__ __align__(16) u16 g_bqkv[768];

__device__ __forceinline__ float b2f(u16 x) {
  unsigned int u = ((unsigned int)x) << 16;
  float f;
  __builtin_memcpy(&f, &u, 4);
  return f;
}
__device__ __forceinline__ u16 f2b(float f) {
  unsigned int u;
  __builtin_memcpy(&u, &f, 4);
  u += 0x7FFFu + ((u >> 16) & 1u);  // round-to-nearest-even
  return (u16)(u >> 16);
}
// async global->LDS, 16B per lane; LDS dest = wave-uniform base + lane*16.
__device__ __forceinline__ void gload16(const u16* g, u16* l) {
  __builtin_amdgcn_global_load_lds(
      (const __attribute__((address_space(1))) unsigned int*)g,
      (__attribute__((address_space(3))) unsigned int*)l, 16, 0, 0);
}
__device__ __forceinline__ void ld4(const u16* p, float* f) {
  uint2 v = *(const uint2*)p;
  f[0] = b2f((u16)(v.x & 0xFFFF));
  f[1] = b2f((u16)(v.x >> 16));
  f[2] = b2f((u16)(v.y & 0xFFFF));
  f[3] = b2f((u16)(v.y >> 16));
}

// --------------------------------------------------------------------------
// dtype probe: even u16 halves of fp32 data hit exp==0xFF w.p. 1/256;
// bf16 N(0,1) data never does.
// --------------------------------------------------------------------------
__global__ __launch_bounds__(256) void probe_kernel(const u16* __restrict__ h) {
  __shared__ int hit;
  if (threadIdx.x == 0) hit = 0;
  __syncthreads();
  int local = 0;
  for (int i = threadIdx.x; i < 8192; i += 256) {
    u16 v = h[2 * i];
    if ((v & 0x7F80) == 0x7F80) local = 1;
  }
  if (local) atomicOr(&hit, 1);
  __syncthreads();
  if (threadIdx.x == 0) g_flag = hit;
}

// canonicalize h -> g_h
__global__ __launch_bounds__(256) void conv_h_kernel(const void* __restrict__ in) {
  const int fp32 = g_flag;
  for (int i = blockIdx.x * 256 + threadIdx.x; i < 16777216;
       i += gridDim.x * 256) {
    g_h[i] = fp32 ? f2b(((const float*)in)[i]) : ((const u16*)in)[i];
  }
}
// canonicalize all 8 weight/bias tensors in one launch
__global__ __launch_bounds__(256) void conv_w_kernel(
    const void* i1, const void* i2, const void* i3, const void* i4,
    const void* i5, const void* i6, const void* i7, const void* i8) {
  const void* srcs[8] = {i1, i2, i3, i4, i5, i6, i7, i8};
  u16* dsts[8] = {g_wperc, g_bperc, g_wup1, g_bup1,
                  g_wup2,  g_bup2,  g_wqkv, g_bqkv};
  const int szs[8] = {6912, 768, 393216, 512, 131072, 256, 196608, 768};
  const int fp32 = g_flag;
  const int stride = gridDim.x * 256;
  for (int gw = blockIdx.x * 256 + threadIdx.x; gw < 730112; gw += stride) {
    int seg = 0, off = gw;
    while (off >= szs[seg]) { off -= szs[seg]; ++seg; }
    dsts[seg][off] = fp32 ? f2b(((const float*)srcs[seg])[off])
                          : ((const u16*)srcs[seg])[off];
  }
}

// --------------------------------------------------------------------------
// grouped 3x3 perception conv (groups=C, 3 outs/group). Block=(b,y) row,
// thread=input channel c. g_h -> g_perc [pix][768] (d=3c+t, group-major).
// --------------------------------------------------------------------------
__global__ __launch_bounds__(256) void perc_kernel() {
  const int by = blockIdx.x;  // b*64 + y
  const int b = by >> 6, y = by & 63;
  const int c = threadIdx.x;
  float w[3][9], bias[3];
#pragma unroll
  for (int t = 0; t < 3; ++t) {
    bias[t] = b2f(g_bperc[3 * c + t]);
#pragma unroll
    for (int j = 0; j < 9; ++j) w[t][j] = b2f(g_wperc[(3 * c + t) * 9 + j]);
  }
  for (int x = 0; x < 64; ++x) {
    float hv[9];
#pragma unroll
    for (int j = 0; j < 9; ++j) {
      int dy = j / 3 - 1, dx = j % 3 - 1;
      int yy = y + dy, xx = x + dx;
      bool ok = ((unsigned)yy < 64u) && ((unsigned)xx < 64u);
      hv[j] = ok ? b2f(g_h[(((size_t)(b * 64 + yy) * 64 + xx) << 8) + c]) : 0.0f;
    }
    const size_t pix = (size_t)(b * 64 + y) * 64 + x;
#pragma unroll
    for (int t = 0; t < 3; ++t) {
      float a = bias[t];
#pragma unroll
      for (int j = 0; j < 9; ++j) a += hv[j] * w[t][j];
      g_perc[pix * 768 + 3 * c + t] = f2b(a);
    }
  }
}

// --------------------------------------------------------------------------
// MFMA bf16 GEMM: C[M,N] = epi(A[M,K] * W[N,K]^T + bias[N])
// BM=BN=128, BK=32, 4 waves 2x2, each 64x64 via 4x4 mfma_f32_16x16x32_bf16.
// Staging via global_load_lds width=16 (LDS stride 32, lane-contiguous).
// XCD swizzle: bid&7 selects an M-slab so all NB n-blocks of an m-block
// share one XCD's L2 (A fetched once per XCD).
// MODE 0: perceived@wup1 +GELU -> hid.  MODE 1: hid@wup2 +h -> hnew.
// MODE 2: hnew@wqkv -> qkv (g_perc reuse).
// --------------------------------------------------------------------------
template <int MODE, int NB>
__global__ __launch_bounds__(256) void gemm_bt(int K) {
  const u16 *A, *Bw, *bias, *resid;
  u16* C;
  if (MODE == 0) { A = g_perc; Bw = g_wup1; bias = g_bup1; resid = nullptr; C = g_hid; }
  if (MODE == 1) { A = g_hid;  Bw = g_wup2; bias = g_bup2; resid = g_h;     C = g_hnew; }
  if (MODE == 2) { A = g_hnew; Bw = g_wqkv; bias = g_bqkv; resid = nullptr; C = g_perc; }
  const int N = NB * 128;

  __shared__ __align__(16) u16 Al[128 * 32];
  __shared__ __align__(16) u16 Bl[128 * 32];
  const int tid = threadIdx.x;
  const int wave = tid >> 6, lane = tid & 63;
  const int ln = lane & 15, quad = lane >> 4;
  // XCD-aware swizzle
  const int mb_per_xcd = (gridDim.x / NB) >> 3;
  const int m_blk = (blockIdx.x & 7) * mb_per_xcd + (blockIdx.x >> 3) / NB;
  const int n_blk = (blockIdx.x >> 3) % NB;
  const int m0 = m_blk * 128, n0 = n_blk * 128;
  const int wm = (wave >> 1) * 64, wn = (wave & 1) * 64;
  const int urow = tid >> 2, ucol = (tid & 3) * 8;  // 16B chunk per thread
  floatx4 acc[4][4] = {};

  for (int k0 = 0; k0 < K; k0 += 32) {
    gload16(&A[(size_t)(m0 + urow) * K + k0 + ucol], &Al[8 * tid]);
    gload16(&A[(size_t)(m0 + urow + 64) * K + k0 + ucol], &Al[8 * (tid + 256)]);
    gload16(&Bw[(size_t)(n0 + urow) * K + k0 + ucol], &Bl[8 * tid]);
    gload16(&Bw[(size_t)(n0 + urow + 64) * K + k0 + ucol], &Bl[8 * (tid + 256)]);
    __syncthreads();
    bf16x8 af[4], bfr[4];
#pragma unroll
    for (int i = 0; i < 4; ++i)
      af[i] = *(const bf16x8*)(&Al[(wm + i * 16 + ln) * 32 + quad * 8]);
#pragma unroll
    for (int j = 0; j < 4; ++j)
      bfr[j] = *(const bf16x8*)(&Bl[(wn + j * 16 + ln) * 32 + quad * 8]);
#pragma unroll
    for (int i = 0; i < 4; ++i)
#pragma unroll
      for (int j = 0; j < 4; ++j)
        acc[i][j] = __builtin_amdgcn_mfma_f32_16x16x32_bf16(af[i], bfr[j],
                                                            acc[i][j], 0, 0, 0);
    __syncthreads();
  }

#pragma unroll
  for (int i = 0; i < 4; ++i) {
#pragma unroll
    for (int rr = 0; rr < 4; ++rr) {
      const int m = m0 + wm + i * 16 + quad * 4 + rr;
#pragma unroll
      for (int j = 0; j < 4; ++j) {
        const int n = n0 + wn + j * 16 + ln;
        float v = acc[i][j][rr] + b2f(bias[n]);
        if (MODE == 0) v = 0.5f * v * (1.0f + erff(v * 0.70710678118654752f));
        if (MODE == 1) v += b2f(resid[(size_t)m * N + n]);
        C[(size_t)m * N + n] = f2b(v);
      }
    }
  }
}

// --------------------------------------------------------------------------
// 3x3 windowed local attention (zero-padded borders). One wave per pixel,
// lane = 4 channels (uint2 loads). OOB neighbor => score 0 in softmax,
// zero value. out = hnew + attn, dtype per g_flag.
// --------------------------------------------------------------------------
__global__ __launch_bounds__(256) void attn_kernel(void* __restrict__ outv) {
  const int wave = threadIdx.x >> 6, lane = threadIdx.x & 63;
  const int pix = blockIdx.x * 4 + wave;
  const int y = (pix >> 6) & 63, x = pix & 63;
  const int c0 = lane * 4;
  float q[4];
  ld4(g_perc + (size_t)pix * 768 + c0, q);
  float s[9];
  int nidx[9];
#pragma unroll
  for (int j = 0; j < 9; ++j) {
    const int dy = j / 3 - 1, dx = j % 3 - 1;
    const int yy = y + dy, xx = x + dx;
    const bool ok = ((unsigned)yy < 64u) && ((unsigned)xx < 64u);
    const int np = pix + dy * 64 + dx;  // same image when ok
    nidx[j] = ok ? np : -1;
    float p = 0.0f;
    if (ok) {
      float kv[4];
      ld4(g_perc + (size_t)np * 768 + 256 + c0, kv);
      p = q[0] * kv[0] + q[1] * kv[1] + q[2] * kv[2] + q[3] * kv[3];
    }
#pragma unroll
    for (int off = 32; off >= 1; off >>= 1) p += __shfl_xor(p, off, 64);
    s[j] = p * 0.0625f;  // 1/sqrt(256)
  }
  float mx = s[0];
#pragma unroll
  for (int j = 1; j < 9; ++j) mx = fmaxf(mx, s[j]);
  float e[9], den = 0.0f;
#pragma unroll
  for (int j = 0; j < 9; ++j) {
    e[j] = expf(s[j] - mx);
    den += e[j];
  }
  const float inv = 1.0f / den;
  float a[4];
  ld4(g_hnew + (size_t)pix * 256 + c0, a);
#pragma unroll
  for (int j = 0; j < 9; ++j) {
    if (nidx[j] >= 0) {
      const float wgt = e[j] * inv;
      float vv[4];
      ld4(g_perc + (size_t)nidx[j] * 768 + 512 + c0, vv);
      a[0] += wgt * vv[0];
      a[1] += wgt * vv[1];
      a[2] += wgt * vv[2];
      a[3] += wgt * vv[3];
    }
  }
  const size_t o = (size_t)pix * 256 + c0;
  if (g_flag) {
    float4 r = {a[0], a[1], a[2], a[3]};
    *(float4*)((float*)outv + o) = r;
  } else {
    uint2 r;
    r.x = (unsigned)f2b(a[0]) | ((unsigned)f2b(a[1]) << 16);
    r.y = (unsigned)f2b(a[2]) | ((unsigned)f2b(a[3]) << 16);
    *(uint2*)((u16*)outv + o) = r;
  }
}

// --------------------------------------------------------------------------
extern "C" void kernel_launch(void* const* d_in, const int* in_sizes, int n_in,
                              void* d_out, int d_out_size, void* d_ws,
                              size_t ws_size, hipStream_t stream) {
  (void)d_ws; (void)ws_size;
  probe_kernel<<<1, 256, 0, stream>>>((const u16*)d_in[0]);
  conv_h_kernel<<<8192, 256, 0, stream>>>(d_in[0]);
  conv_w_kernel<<<360, 256, 0, stream>>>(d_in[1], d_in[2], d_in[3], d_in[4],
                                         d_in[5], d_in[6], d_in[7], d_in[8]);
  perc_kernel<<<1024, 256, 0, stream>>>();
  // hid = GELU(perceived @ w_up1^T + b_up1)   [65536 x 512, K=768]
  gemm_bt<0, 4><<<2048, 256, 0, stream>>>(768);
  // h_new = h + hid @ w_up2^T + b_up2         [65536 x 256, K=512]
  gemm_bt<1, 2><<<1024, 256, 0, stream>>>(512);
  // qkv = h_new @ w_qkv^T + b_qkv             [65536 x 768, K=256]
  gemm_bt<2, 6><<<3072, 256, 0, stream>>>(256);
  // out = h_new + local_attn(qkv)
  attn_kernel<<<16384, 256, 0, stream>>>(d_out);
}

// Round 5
// 486.808 us; speedup vs baseline: 1.3205x; 1.1833x over previous
//
#include <hip/hip_runtime.h>
#include <math.h>

// B=16, H=64, W=64, C=256; M=65536 pixels. Inputs fp32 (runtime-detected,
// canonicalized to bf16 device globals). Compute: bf16 MFMA, fp32 accum.
// R5: perc_kernel rewritten (sliding 3x3 window, 8B loads, 24B/lane packed
// stores, weights registered via LDS); conv_h vectorized (float4->uint2).

typedef unsigned short u16;
typedef __bf16 bf16x8 __attribute__((ext_vector_type(8)));
typedef float floatx4 __attribute__((ext_vector_type(4)));

__device__ int g_flag;  // 0 = bf16 inputs, 1 = fp32 inputs
__device__ __align__(16) u16 g_h[16777216];     // canonical bf16 h  [65536,256]
__device__ __align__(16) u16 g_perc[50331648];  // perceived/qkv     [65536,768]
__device__ __align__(16) u16 g_hid[33554432];   // hid               [65536,512]
__device__ __align__(16) u16 g_hnew[16777216];  // h_new             [65536,256]
__device__ __align__(16) u16 g_wperc[6912];
__device__ __align__(16) u16 g_bperc[768];
__device__ __align__(16) u16 g_wup1[393216];
__device__ __align__(16) u16 g_bup1[512];
__device__ __align__(16) u16 g_wup2[131072];
__device__ __align__(16) u16 g_bup2[256];
__device__ __align__(16) u16 g_wqkv[196608];
__device__ __align__(16) u16 g_bqkv[768];

__device__ __forceinline__ float b2f(u16 x) {
  unsigned int u = ((unsigned int)x) << 16;
  float f;
  __builtin_memcpy(&f, &u, 4);
  return f;
}
__device__ __forceinline__ u16 f2b(float f) {
  unsigned int u;
  __builtin_memcpy(&u, &f, 4);
  u += 0x7FFFu + ((u >> 16) & 1u);  // round-to-nearest-even
  return (u16)(u >> 16);
}
// async global->LDS, 16B per lane; LDS dest = wave-uniform base + lane*16.
__device__ __forceinline__ void gload16(const u16* g, u16* l) {
  __builtin_amdgcn_global_load_lds(
      (const __attribute__((address_space(1))) unsigned int*)g,
      (__attribute__((address_space(3))) unsigned int*)l, 16, 0, 0);
}
__device__ __forceinline__ void ld4(const u16* p, float* f) {
  uint2 v = *(const uint2*)p;
  f[0] = b2f((u16)(v.x & 0xFFFF));
  f[1] = b2f((u16)(v.x >> 16));
  f[2] = b2f((u16)(v.y & 0xFFFF));
  f[3] = b2f((u16)(v.y >> 16));
}

// --------------------------------------------------------------------------
// dtype probe: even u16 halves of fp32 data hit exp==0xFF w.p. 1/256;
// bf16 N(0,1) data never does.
// --------------------------------------------------------------------------
__global__ __launch_bounds__(256) void probe_kernel(const u16* __restrict__ h) {
  __shared__ int hit;
  if (threadIdx.x == 0) hit = 0;
  __syncthreads();
  int local = 0;
  for (int i = threadIdx.x; i < 8192; i += 256) {
    u16 v = h[2 * i];
    if ((v & 0x7F80) == 0x7F80) local = 1;
  }
  if (local) atomicOr(&hit, 1);
  __syncthreads();
  if (threadIdx.x == 0) g_flag = hit;
}

// canonicalize h -> g_h (4 elems/thread, single pass)
__global__ __launch_bounds__(256) void conv_h_kernel(const void* __restrict__ in) {
  const int i = blockIdx.x * 256 + threadIdx.x;  // group of 4 elements
  if (g_flag) {
    const float4 v = ((const float4*)in)[i];
    uint2 r;
    r.x = (unsigned)f2b(v.x) | ((unsigned)f2b(v.y) << 16);
    r.y = (unsigned)f2b(v.z) | ((unsigned)f2b(v.w) << 16);
    ((uint2*)g_h)[i] = r;
  } else {
    ((uint2*)g_h)[i] = ((const uint2*)in)[i];
  }
}
// canonicalize all 8 weight/bias tensors in one launch
__global__ __launch_bounds__(256) void conv_w_kernel(
    const void* i1, const void* i2, const void* i3, const void* i4,
    const void* i5, const void* i6, const void* i7, const void* i8) {
  const void* srcs[8] = {i1, i2, i3, i4, i5, i6, i7, i8};
  u16* dsts[8] = {g_wperc, g_bperc, g_wup1, g_bup1,
                  g_wup2,  g_bup2,  g_wqkv, g_bqkv};
  const int szs[8] = {6912, 768, 393216, 512, 131072, 256, 196608, 768};
  const int fp32 = g_flag;
  const int stride = gridDim.x * 256;
  for (int gw = blockIdx.x * 256 + threadIdx.x; gw < 730112; gw += stride) {
    int seg = 0, off = gw;
    while (off >= szs[seg]) { off -= szs[seg]; ++seg; }
    dsts[seg][off] = fp32 ? f2b(((const float*)srcs[seg])[off])
                          : ((const u16*)srcs[seg])[off];
  }
}

// --------------------------------------------------------------------------
// grouped 3x3 perception conv. Block=(b,y) row; wave=16-px x-strip (xi),
// lane=4-channel group. Sliding 3-col register window, 8B loads, weights
// registered from LDS, 24B/lane packed stores. g_h -> g_perc [pix][768].
// --------------------------------------------------------------------------
__global__ __launch_bounds__(256) void perc_kernel() {
  __shared__ __align__(16) u16 sw[6912];
  __shared__ __align__(16) u16 sb[768];
  const int bid = blockIdx.x;  // b*64 + y
  const int b = bid >> 6, y = bid & 63;
  const int xi = threadIdx.x >> 6;  // wave id: x-strip
  const int cg = threadIdx.x & 63;  // channel group (4 ch)
  const int c0 = cg * 4;
  for (int i = threadIdx.x; i < 6912; i += 256) sw[i] = g_wperc[i];
  for (int i = threadIdx.x; i < 768; i += 256) sb[i] = g_bperc[i];
  __syncthreads();
  float w[4][27], bias[4][3];
#pragma unroll
  for (int ch = 0; ch < 4; ++ch) {
#pragma unroll
    for (int t = 0; t < 3; ++t) {
      bias[ch][t] = b2f(sb[3 * (c0 + ch) + t]);
#pragma unroll
      for (int j = 0; j < 9; ++j)
        w[ch][t * 9 + j] = b2f(sw[(3 * (c0 + ch) + t) * 9 + j]);
    }
  }
  float hv[3][3][4];  // [row][colslot][ch]
  auto loadcol = [&](int xx, int cc) {
#pragma unroll
    for (int r = 0; r < 3; ++r) {
      const int yy = y - 1 + r;
      const bool ok = ((unsigned)yy < 64u) && ((unsigned)xx < 64u);
      if (ok) {
        const uint2 v =
            *(const uint2*)&g_h[(((size_t)(b * 64 + yy) * 64) + xx) * 256 + c0];
        hv[r][cc][0] = b2f((u16)(v.x & 0xFFFF));
        hv[r][cc][1] = b2f((u16)(v.x >> 16));
        hv[r][cc][2] = b2f((u16)(v.y & 0xFFFF));
        hv[r][cc][3] = b2f((u16)(v.y >> 16));
      } else {
        hv[r][cc][0] = 0.0f; hv[r][cc][1] = 0.0f;
        hv[r][cc][2] = 0.0f; hv[r][cc][3] = 0.0f;
      }
    }
  };
  const int x0 = xi * 16;
  loadcol(x0 - 1, 0);
  loadcol(x0, 1);
#pragma unroll
  for (int k = 0; k < 16; ++k) {
    const int x = x0 + k;
    loadcol(x + 1, (k + 2) % 3);
    const int cL = k % 3, cM = (k + 1) % 3, cR = (k + 2) % 3;
    const size_t pix = (size_t)(b * 64 + y) * 64 + x;
    u16* op = &g_perc[pix * 768 + 3 * c0];
    unsigned pk[6];
#pragma unroll
    for (int ch = 0; ch < 4; ++ch) {
#pragma unroll
      for (int t = 0; t < 3; ++t) {
        const float* wt = &w[ch][t * 9];
        float a = bias[ch][t];
        a += hv[0][cL][ch] * wt[0] + hv[0][cM][ch] * wt[1] + hv[0][cR][ch] * wt[2];
        a += hv[1][cL][ch] * wt[3] + hv[1][cM][ch] * wt[4] + hv[1][cR][ch] * wt[5];
        a += hv[2][cL][ch] * wt[6] + hv[2][cM][ch] * wt[7] + hv[2][cR][ch] * wt[8];
        const int o = 3 * ch + t;
        const unsigned bb = f2b(a);
        if (o & 1) pk[o >> 1] |= bb << 16; else pk[o >> 1] = bb;
      }
    }
    uint2 r0; r0.x = pk[0]; r0.y = pk[1];
    uint2 r1; r1.x = pk[2]; r1.y = pk[3];
    uint2 r2; r2.x = pk[4]; r2.y = pk[5];
    *(uint2*)(op) = r0;
    *(uint2*)(op + 4) = r1;
    *(uint2*)(op + 8) = r2;
  }
}

// --------------------------------------------------------------------------
// MFMA bf16 GEMM: C[M,N] = epi(A[M,K] * W[N,K]^T + bias[N])
// BM=BN=128, BK=32, 4 waves 2x2, each 64x64 via 4x4 mfma_f32_16x16x32_bf16.
// global_load_lds width=16 staging (LDS stride 32), XCD-aware swizzle.
// MODE 0: perceived@wup1 +GELU -> hid.  MODE 1: hid@wup2 +h -> hnew.
// MODE 2: hnew@wqkv -> qkv (g_perc reuse).
// --------------------------------------------------------------------------
template <int MODE, int NB>
__global__ __launch_bounds__(256) void gemm_bt(int K) {
  const u16 *A, *Bw, *bias, *resid;
  u16* C;
  if (MODE == 0) { A = g_perc; Bw = g_wup1; bias = g_bup1; resid = nullptr; C = g_hid; }
  if (MODE == 1) { A = g_hid;  Bw = g_wup2; bias = g_bup2; resid = g_h;     C = g_hnew; }
  if (MODE == 2) { A = g_hnew; Bw = g_wqkv; bias = g_bqkv; resid = nullptr; C = g_perc; }
  const int N = NB * 128;

  __shared__ __align__(16) u16 Al[128 * 32];
  __shared__ __align__(16) u16 Bl[128 * 32];
  const int tid = threadIdx.x;
  const int wave = tid >> 6, lane = tid & 63;
  const int ln = lane & 15, quad = lane >> 4;
  const int mb_per_xcd = (gridDim.x / NB) >> 3;
  const int m_blk = (blockIdx.x & 7) * mb_per_xcd + (blockIdx.x >> 3) / NB;
  const int n_blk = (blockIdx.x >> 3) % NB;
  const int m0 = m_blk * 128, n0 = n_blk * 128;
  const int wm = (wave >> 1) * 64, wn = (wave & 1) * 64;
  const int urow = tid >> 2, ucol = (tid & 3) * 8;
  floatx4 acc[4][4] = {};

  for (int k0 = 0; k0 < K; k0 += 32) {
    gload16(&A[(size_t)(m0 + urow) * K + k0 + ucol], &Al[8 * tid]);
    gload16(&A[(size_t)(m0 + urow + 64) * K + k0 + ucol], &Al[8 * (tid + 256)]);
    gload16(&Bw[(size_t)(n0 + urow) * K + k0 + ucol], &Bl[8 * tid]);
    gload16(&Bw[(size_t)(n0 + urow + 64) * K + k0 + ucol], &Bl[8 * (tid + 256)]);
    __syncthreads();
    bf16x8 af[4], bfr[4];
#pragma unroll
    for (int i = 0; i < 4; ++i)
      af[i] = *(const bf16x8*)(&Al[(wm + i * 16 + ln) * 32 + quad * 8]);
#pragma unroll
    for (int j = 0; j < 4; ++j)
      bfr[j] = *(const bf16x8*)(&Bl[(wn + j * 16 + ln) * 32 + quad * 8]);
#pragma unroll
    for (int i = 0; i < 4; ++i)
#pragma unroll
      for (int j = 0; j < 4; ++j)
        acc[i][j] = __builtin_amdgcn_mfma_f32_16x16x32_bf16(af[i], bfr[j],
                                                            acc[i][j], 0, 0, 0);
    __syncthreads();
  }

#pragma unroll
  for (int i = 0; i < 4; ++i) {
#pragma unroll
    for (int rr = 0; rr < 4; ++rr) {
      const int m = m0 + wm + i * 16 + quad * 4 + rr;
#pragma unroll
      for (int j = 0; j < 4; ++j) {
        const int n = n0 + wn + j * 16 + ln;
        float v = acc[i][j][rr] + b2f(bias[n]);
        if (MODE == 0) v = 0.5f * v * (1.0f + erff(v * 0.70710678118654752f));
        if (MODE == 1) v += b2f(resid[(size_t)m * N + n]);
        C[(size_t)m * N + n] = f2b(v);
      }
    }
  }
}

// --------------------------------------------------------------------------
// 3x3 windowed local attention (zero-padded borders). One wave per pixel,
// lane = 4 channels (uint2 loads). OOB neighbor => score 0 in softmax,
// zero value. out = hnew + attn, dtype per g_flag.
// --------------------------------------------------------------------------
__global__ __launch_bounds__(256) void attn_kernel(void* __restrict__ outv) {
  const int wave = threadIdx.x >> 6, lane = threadIdx.x & 63;
  const int pix = blockIdx.x * 4 + wave;
  const int y = (pix >> 6) & 63, x = pix & 63;
  const int c0 = lane * 4;
  float q[4];
  ld4(g_perc + (size_t)pix * 768 + c0, q);
  float s[9];
  int nidx[9];
#pragma unroll
  for (int j = 0; j < 9; ++j) {
    const int dy = j / 3 - 1, dx = j % 3 - 1;
    const int yy = y + dy, xx = x + dx;
    const bool ok = ((unsigned)yy < 64u) && ((unsigned)xx < 64u);
    const int np = pix + dy * 64 + dx;  // same image when ok
    nidx[j] = ok ? np : -1;
    float p = 0.0f;
    if (ok) {
      float kv[4];
      ld4(g_perc + (size_t)np * 768 + 256 + c0, kv);
      p = q[0] * kv[0] + q[1] * kv[1] + q[2] * kv[2] + q[3] * kv[3];
    }
#pragma unroll
    for (int off = 32; off >= 1; off >>= 1) p += __shfl_xor(p, off, 64);
    s[j] = p * 0.0625f;  // 1/sqrt(256)
  }
  float mx = s[0];
#pragma unroll
  for (int j = 1; j < 9; ++j) mx = fmaxf(mx, s[j]);
  float e[9], den = 0.0f;
#pragma unroll
  for (int j = 0; j < 9; ++j) {
    e[j] = expf(s[j] - mx);
    den += e[j];
  }
  const float inv = 1.0f / den;
  float a[4];
  ld4(g_hnew + (size_t)pix * 256 + c0, a);
#pragma unroll
  for (int j = 0; j < 9; ++j) {
    if (nidx[j] >= 0) {
      const float wgt = e[j] * inv;
      float vv[4];
      ld4(g_perc + (size_t)nidx[j] * 768 + 512 + c0, vv);
      a[0] += wgt * vv[0];
      a[1] += wgt * vv[1];
      a[2] += wgt * vv[2];
      a[3] += wgt * vv[3];
    }
  }
  const size_t o = (size_t)pix * 256 + c0;
  if (g_flag) {
    float4 r = {a[0], a[1], a[2], a[3]};
    *(float4*)((float*)outv + o) = r;
  } else {
    uint2 r;
    r.x = (unsigned)f2b(a[0]) | ((unsigned)f2b(a[1]) << 16);
    r.y = (unsigned)f2b(a[2]) | ((unsigned)f2b(a[3]) << 16);
    *(uint2*)((u16*)outv + o) = r;
  }
}

// --------------------------------------------------------------------------
extern "C" void kernel_launch(void* const* d_in, const int* in_sizes, int n_in,
                              void* d_out, int d_out_size, void* d_ws,
                              size_t ws_size, hipStream_t stream) {
  (void)d_ws; (void)ws_size;
  probe_kernel<<<1, 256, 0, stream>>>((const u16*)d_in[0]);
  conv_h_kernel<<<16384, 256, 0, stream>>>(d_in[0]);
  conv_w_kernel<<<360, 256, 0, stream>>>(d_in[1], d_in[2], d_in[3], d_in[4],
                                         d_in[5], d_in[6], d_in[7], d_in[8]);
  perc_kernel<<<1024, 256, 0, stream>>>();
  // hid = GELU(perceived @ w_up1^T + b_up1)   [65536 x 512, K=768]
  gemm_bt<0, 4><<<2048, 256, 0, stream>>>(768);
  // h_new = h + hid @ w_up2^T + b_up2         [65536 x 256, K=512]
  gemm_bt<1, 2><<<1024, 256, 0, stream>>>(512);
  // qkv = h_new @ w_qkv^T + b_qkv             [65536 x 768, K=256]
  gemm_bt<2, 6><<<3072, 256, 0, stream>>>(256);
  // out = h_new + local_attn(qkv)
  attn_kernel<<<16384, 256, 0, stream>>>(d_out);
}